// Round 6
// baseline (184.972 us; speedup 1.0000x reference)
//
#include <hip/hip_runtime.h>
#include <hip/hip_bf16.h>

// B=2, T=2048, D=1024, H=16, Hd=64. Inputs/outputs f32; compute bf16 MFMA.

typedef __bf16 bf16;
typedef bf16 bf16x8 __attribute__((ext_vector_type(8)));
typedef bf16 bf16x4 __attribute__((ext_vector_type(4)));
typedef float f32x4 __attribute__((ext_vector_type(4)));

#define MFMA16(a, b, c) __builtin_amdgcn_mfma_f32_16x16x32_bf16((a), (b), (c), 0, 0, 0)

static constexpr int D_MODEL = 1024;
static constexpr int NH = 16;
static constexpr int HD = 64;
static constexpr int SEQ = 2048;
static constexpr int NB = 2;
static constexpr float QSCALE = 0.125f * 1.44269504088896340736f; // 1/sqrt(64)*log2(e)

__device__ __forceinline__ bf16x8 cvt8(const float* p) {
    float4 u0 = *(const float4*)p;
    float4 u1 = *(const float4*)(p + 4);
    bf16x8 v = { (bf16)u0.x, (bf16)u0.y, (bf16)u0.z, (bf16)u0.w,
                 (bf16)u1.x, (bf16)u1.y, (bf16)u1.z, (bf16)u1.w };
    return v;
}

// async global->LDS, 16 B per lane (LDS dest = wave-uniform base + lane*16).
__device__ __forceinline__ void async16(const bf16* g, bf16* l) {
    __builtin_amdgcn_global_load_lds(
        (const __attribute__((address_space(1))) void*)g,
        (__attribute__((address_space(3))) void*)l, 16, 0, 0);
}

// ---------------------------------------------------------------------------
// Kernel 0: f32 -> bf16 cast (vector x8).
// ---------------------------------------------------------------------------
__global__ __launch_bounds__(256)
void k_cast(const float* __restrict__ in, bf16* __restrict__ out, int n8)
{
    int i = blockIdx.x * 256 + threadIdx.x;
    if (i < n8) *(bf16x8*)&out[(size_t)i * 8] = cvt8(&in[(size_t)i * 8]);
}

// ---------------------------------------------------------------------------
// Kernel 1: QKV projection, 128x128 tile, BK=32 — R1 version (syncthreads,
// single-buffer). R5 measured the counted-vmcnt pipeline variant at 45.4 µs
// vs <=42 for this one: at 12 waves/CU, wave-level TLP already hides the
// staging drain (m131-m140 precedent); the extra barrier per K-step net-lost.
// Q -> [B,H,T,64] (pre-scaled), K -> [B,H,T,64], V -> transposed [B,H,64,T].
// ---------------------------------------------------------------------------
__global__ __launch_bounds__(256)
void k_qkv(const bf16* __restrict__ x, const bf16* __restrict__ w,
           const float* __restrict__ bias,
           bf16* __restrict__ Qb, bf16* __restrict__ Kb, bf16* __restrict__ VbT)
{
    __shared__ bf16 As[128 * 32];   // 8 KB, flat
    __shared__ bf16 Ws[128 * 32];

    const int tid  = threadIdx.x;
    const int wv   = tid >> 6;
    const int lane = tid & 63;
    const int lr   = lane & 15;
    const int lk   = lane >> 4;
    const int wm   = wv >> 1, wn = wv & 1;
    const int m0   = blockIdx.x * 128;
    const int n0   = blockIdx.y * 128;

    const int sRow = tid >> 2;           // 0..63
    const int sCol = (tid & 3) * 8;      // 0,8,16,24
    const int sOff = sRow * 32 + sCol;   // = 16*tid bytes

    f32x4 acc[4][4] = {};

    for (int kt = 0; kt < 1024; kt += 32) {
        __syncthreads();
        async16(&x[(size_t)(m0 + sRow     ) * 1024 + kt + sCol], &As[sOff]);
        async16(&x[(size_t)(m0 + 64 + sRow) * 1024 + kt + sCol], &As[64 * 32 + sOff]);
        async16(&w[(size_t)(n0 + sRow     ) * 1024 + kt + sCol], &Ws[sOff]);
        async16(&w[(size_t)(n0 + 64 + sRow) * 1024 + kt + sCol], &Ws[64 * 32 + sOff]);
        __syncthreads();

        bf16x8 a[4], b[4];
        #pragma unroll
        for (int i = 0; i < 4; i++) {
            a[i] = *(const bf16x8*)&As[(wm * 64 + i * 16 + lr) * 32 + lk * 8];
            b[i] = *(const bf16x8*)&Ws[(wn * 64 + i * 16 + lr) * 32 + lk * 8];
        }
        #pragma unroll
        for (int i = 0; i < 4; i++)
            #pragma unroll
            for (int j = 0; j < 4; j++)
                acc[i][j] = MFMA16(a[i], b[j], acc[i][j]);
    }

    // C/D layout: col = lane&15, row = (lane>>4)*4 + reg
    #pragma unroll
    for (int i = 0; i < 4; i++) {
        #pragma unroll
        for (int j = 0; j < 4; j++) {
            const int gm0 = m0 + wm * 64 + i * 16 + lk * 4;
            const int gn  = n0 + wn * 64 + j * 16 + lr;
            const int sel = gn >> 10;
            const int rem = gn & 1023;
            const int h   = rem >> 6;
            const int hd  = rem & 63;
            const int bb  = gm0 >> 11;
            const int t0  = gm0 & 2047;
            if (sel == 2) {
                bf16x4 p;
                #pragma unroll
                for (int r = 0; r < 4; r++) p[r] = (bf16)(acc[i][j][r] + bias[gn]);
                *(bf16x4*)&VbT[((size_t)(bb * NH + h) * HD + hd) * SEQ + t0] = p;
            } else {
                #pragma unroll
                for (int r = 0; r < 4; r++) {
                    float v = acc[i][j][r] + bias[gn];
                    size_t idx = ((size_t)(bb * NH + h) * SEQ + t0 + r) * HD + hd;
                    if (sel == 0) Qb[idx] = (bf16)(v * QSCALE);
                    else          Kb[idx] = (bf16)v;
                }
            }
        }
    }
}

// ---------------------------------------------------------------------------
// Kernel 2: causal flash attention.
// R15: QBLK=128 via 8 waves x 16 q (512 threads) — KV amortization WITHOUT
// R2's failure modes. Per-wave state/inner-loop/VGPR identical to the proven
// R1 wave (16 q rows, qf[2], ot[4], s[4]); we add waves instead of fattening
// them. Tiles per bh: 528 -> 272 (K/V HBM refetch and stage events ~halve);
// staging = 2 loads/thread/tile (vmcnt(2)); LDS 48 KB; grid 512 = 2
// blocks/CU x 8 waves = 16 waves/CU — same 50% occupancy ceiling as R1
// (R2's QBLK=128 had 8 waves/CU + VGPR 80, which is what regressed).
// Serpentine parity for the (16,32) grid: CU-paired blocks are Δid=256 ⇒
// Δby=16, so parity must flip under by->by+16: ((bh>>3)^(bh>>4))&1.
// Carries R1's proven pipeline: double-buffered K/V via global_load_lds one
// tile ahead, counted vmcnt + raw s_barrier, 16B-chunk XOR swizzle with
// pre-swizzled global source (linear LDS dest), no-max softmax with HW exp,
// transposed scores S^T = K·Q^T.
// ---------------------------------------------------------------------------
__global__ __launch_bounds__(512)
void k_attn(const bf16* __restrict__ Qb, const bf16* __restrict__ Kb,
            const bf16* __restrict__ VbT, bf16* __restrict__ AO)
{
    __shared__ bf16 Ks[2][64 * 64];   // [buf][key][hd], swizzled, 8 KB each
    __shared__ bf16 Vt[2][64 * 64];   // [buf][hd][key], swizzled
    __shared__ bf16 Ps[128 * 64];     // [q][key], swizzled, wave-local rows
    // total 48 KB

    const int tid  = threadIdx.x;
    const int wv   = tid >> 6;        // 0..7
    const int lane = tid & 63;
    const int lr   = lane & 15;
    const int lk   = lane >> 4;
    const int bh   = blockIdx.y;
    const int par  = ((bh >> 3) ^ (bh >> 4)) & 1;
    const int qt   = par ? (15 - (int)blockIdx.x) : (int)blockIdx.x;

    const bf16* Qp  = Qb  + (size_t)bh * SEQ * HD;
    const bf16* Kp  = Kb  + (size_t)bh * SEQ * HD;
    const bf16* Vtp = VbT + (size_t)bh * HD * SEQ;

    const int qbase = qt * 128 + wv * 16;     // this wave's first query row
    const int qg    = qbase + lr;             // this lane's query row

    // Q as B-operand: b[n=lr][k=lk*8+e] (loop-invariant)
    bf16x8 qf[2];
    qf[0] = *(const bf16x8*)&Qp[(size_t)qg * HD +      lk * 8];
    qf[1] = *(const bf16x8*)&Qp[(size_t)qg * HD + 32 + lk * 8];

    f32x4 ot[4] = {};          // O^T: col=q(=lr), row=hd=jh*16+lk*4+r
    float lsum = 0.f;

    // Staging: 512 threads x 16B = one full 8 KB tile per round.
    // LDS dest linear (elem = tid*8); global source chunk pre-swizzled:
    // chunk = (tid&7) ^ (row&7)  (both-sides-or-neither).
    const int srow   = tid >> 3;                       // 0..63
    const int sgcol  = ((tid & 7) ^ (srow & 7)) * 8;   // swizzled global col
    const int sldse  = tid * 8;                        // lds elem
    const int swz    = lr & 7;                         // read-side swizzle key

    auto stage = [&](int buf, int k0) {
        async16(&Kp [(size_t)(k0 + srow) * HD  + sgcol],      &Ks[buf][sldse]);
        async16(&Vtp[(size_t)srow        * SEQ + k0 + sgcol], &Vt[buf][sldse]);
    };

    stage(0, 0);   // prologue: tile 0 in flight (2 loads)

    const int ktMax = 2 * qt + 1;  // key tiles 0 .. 2qt+1 cover keys < (qt+1)*128

    for (int kt = 0; kt <= ktMax; kt++) {
        const int p = kt & 1;
        if (kt < ktMax) {
            stage(p ^ 1, (kt + 1) * 64);                    // prefetch next tile
            asm volatile("s_waitcnt vmcnt(2)" ::: "memory"); // cur landed, next 2 in flight
        } else {
            asm volatile("s_waitcnt vmcnt(0)" ::: "memory"); // last tile: drain
        }
        __builtin_amdgcn_s_barrier();

        // S^T[key][q]: A = K rows (LDS), B = Q frags; row=key=j*16+lk*4+r, col=q=lr
        f32x4 s[4] = {};
        #pragma unroll
        for (int j = 0; j < 4; j++) {
            #pragma unroll
            for (int c = 0; c < 2; c++) {
                bf16x8 ka = *(const bf16x8*)
                    &Ks[p][(j * 16 + lr) * 64 + (((4 * c + lk) ^ swz) << 3)];
                s[j] = MFMA16(ka, qf[c], s[j]);
            }
        }

        // no-max softmax with HW exp; per-lane mask on tiles that can cross
        // this wave's causal boundary (key_max = kt*64+63 vs q_min = qbase)
        const int k0 = kt * 64;
        const bool diag = (k0 + 63 > qbase);
        #pragma unroll
        for (int j = 0; j < 4; j++) {
            const int keyb = k0 + j * 16 + lk * 4;
            f32x4 pv;
            #pragma unroll
            for (int r = 0; r < 4; r++) {
                float e = __builtin_amdgcn_exp2f(s[j][r]);
                if (diag) e = (keyb + r > qg) ? 0.f : e;
                pv[r] = e;
            }
            s[j] = pv;
            lsum += (pv[0] + pv[1]) + (pv[2] + pv[3]);
        }

        // P -> LDS [q][key] (swizzled 16B chunks; wave-local rows, no barrier)
        #pragma unroll
        for (int j = 0; j < 4; j++) {
            bf16x4 p4 = { (bf16)s[j][0], (bf16)s[j][1], (bf16)s[j][2], (bf16)s[j][3] };
            *(bf16x4*)&Ps[(wv * 16 + lr) * 64 +
                          (((2 * j + (lk >> 1)) ^ swz) << 3) + ((lk & 1) << 2)] = p4;
        }

        // O^T += Vt · P^T : MFMA(a = Vt rows [hd][key], b = Ps rows [q][key])
        #pragma unroll
        for (int c = 0; c < 2; c++) {
            bf16x8 pb = *(const bf16x8*)
                &Ps[(wv * 16 + lr) * 64 + (((4 * c + lk) ^ swz) << 3)];
            #pragma unroll
            for (int jh = 0; jh < 4; jh++) {
                bf16x8 va = *(const bf16x8*)
                    &Vt[p][(jh * 16 + lr) * 64 + (((4 * c + lk) ^ swz) << 3)];
                ot[jh] = MFMA16(va, pb, ot[jh]);
            }
        }

        asm volatile("" ::: "memory");
        __builtin_amdgcn_s_barrier();   // protect buf[p^1] before next stage
    }

    // final l reduction: 2 shfls once per kernel (lanes lr, lr+16, lr+32, lr+48)
    lsum += __shfl_xor(lsum, 16);
    lsum += __shfl_xor(lsum, 32);

    // epilogue: AO[b, q, h_*64 + hd] = O/l ; lane writes 4 consecutive hd (b64)
    const float inv = 1.0f / lsum;
    const int b_ = bh >> 4, h_ = bh & 15;
    const size_t base = ((size_t)(b_ * SEQ + qg)) * D_MODEL + h_ * HD;
    #pragma unroll
    for (int jh = 0; jh < 4; jh++) {
        bf16x4 o4 = { (bf16)(ot[jh][0] * inv), (bf16)(ot[jh][1] * inv),
                      (bf16)(ot[jh][2] * inv), (bf16)(ot[jh][3] * inv) };
        *(bf16x4*)&AO[base + jh * 16 + lk * 4] = o4;
    }
}

// ---------------------------------------------------------------------------
// Kernel 3: output projection, 128x64 tile, BK=32 — R1 version (syncthreads,
// single-buffer; pipeline variant regressed, see k_qkv note).
// ---------------------------------------------------------------------------
__global__ __launch_bounds__(256)
void k_oproj(const bf16* __restrict__ a_, const bf16* __restrict__ w,
             const float* __restrict__ bias, float* __restrict__ out)
{
    __shared__ bf16 As[128 * 32];
    __shared__ bf16 Ws[64 * 32];

    const int tid  = threadIdx.x;
    const int wv   = tid >> 6;
    const int lane = tid & 63;
    const int lr   = lane & 15;
    const int lk   = lane >> 4;
    const int wm   = wv >> 1, wn = wv & 1;
    const int m0   = blockIdx.x * 128;
    const int n0   = blockIdx.y * 64;

    const int sRow = tid >> 2;
    const int sCol = (tid & 3) * 8;
    const int sOff = sRow * 32 + sCol;

    f32x4 acc[4][2] = {};

    for (int kt = 0; kt < 1024; kt += 32) {
        __syncthreads();
        async16(&a_[(size_t)(m0 + sRow     ) * 1024 + kt + sCol], &As[sOff]);
        async16(&a_[(size_t)(m0 + 64 + sRow) * 1024 + kt + sCol], &As[64 * 32 + sOff]);
        async16(&w [(size_t)(n0 + sRow     ) * 1024 + kt + sCol], &Ws[sOff]);
        __syncthreads();

        bf16x8 a[4], b[2];
        #pragma unroll
        for (int i = 0; i < 4; i++)
            a[i] = *(const bf16x8*)&As[(wm * 64 + i * 16 + lr) * 32 + lk * 8];
        #pragma unroll
        for (int j = 0; j < 2; j++)
            b[j] = *(const bf16x8*)&Ws[(wn * 32 + j * 16 + lr) * 32 + lk * 8];
        #pragma unroll
        for (int i = 0; i < 4; i++)
            #pragma unroll
            for (int j = 0; j < 2; j++)
                acc[i][j] = MFMA16(a[i], b[j], acc[i][j]);
    }

    #pragma unroll
    for (int i = 0; i < 4; i++) {
        #pragma unroll
        for (int j = 0; j < 2; j++) {
            #pragma unroll
            for (int r = 0; r < 4; r++) {
                int gm = m0 + wm * 64 + i * 16 + lk * 4 + r;
                int gn = n0 + wn * 32 + j * 16 + lr;
                out[(size_t)gm * 1024 + gn] = acc[i][j][r] + bias[gn];
            }
        }
    }
}

// ---------------------------------------------------------------------------
extern "C" void kernel_launch(void* const* d_in, const int* in_sizes, int n_in,
                              void* d_out, int out_size, void* d_ws, size_t ws_size,
                              hipStream_t stream)
{
    const float* x     = (const float*)d_in[0];
    const float* qkv_w = (const float*)d_in[1];
    const float* qkv_b = (const float*)d_in[2];
    const float* out_w = (const float*)d_in[3];
    const float* out_b = (const float*)d_in[4];
    float* out = (float*)d_out;

    const size_t SZ = (size_t)NB * NH * SEQ * HD;      // 4,194,304
    bf16* Qb  = (bf16*)d_ws;
    bf16* Kb  = Qb + SZ;
    bf16* VbT = Kb + SZ;
    bf16* AO  = VbT + SZ;
    bf16* xb  = AO + SZ;
    bf16* wqb = xb + SZ;
    bf16* wob = wqb + (size_t)3 * D_MODEL * D_MODEL;

    hipLaunchKernelGGL(k_cast, dim3(2048), dim3(256), 0, stream, x,     xb,  524288);
    hipLaunchKernelGGL(k_cast, dim3(1536), dim3(256), 0, stream, qkv_w, wqb, 393216);
    hipLaunchKernelGGL(k_cast, dim3(512),  dim3(256), 0, stream, out_w, wob, 131072);

    hipLaunchKernelGGL(k_qkv, dim3(32, 24), dim3(256), 0, stream,
                       xb, wqb, qkv_b, Qb, Kb, VbT);
    hipLaunchKernelGGL(k_attn, dim3(16, 32), dim3(512), 0, stream,
                       Qb, Kb, VbT, AO);
    hipLaunchKernelGGL(k_oproj, dim3(32, 16), dim3(256), 0, stream,
                       AO, wob, out_b, out);
}

// Round 7
// 171.480 us; speedup vs baseline: 1.0787x; 1.0787x over previous
//
#include <hip/hip_runtime.h>
#include <hip/hip_bf16.h>

// B=2, T=2048, D=1024, H=16, Hd=64. Inputs/outputs f32; compute bf16 MFMA.

typedef __bf16 bf16;
typedef bf16 bf16x8 __attribute__((ext_vector_type(8)));
typedef bf16 bf16x4 __attribute__((ext_vector_type(4)));
typedef float f32x4 __attribute__((ext_vector_type(4)));

#define MFMA16(a, b, c) __builtin_amdgcn_mfma_f32_16x16x32_bf16((a), (b), (c), 0, 0, 0)

static constexpr int D_MODEL = 1024;
static constexpr int NH = 16;
static constexpr int HD = 64;
static constexpr int SEQ = 2048;
static constexpr int NB = 2;
static constexpr float QSCALE = 0.125f * 1.44269504088896340736f; // 1/sqrt(64)*log2(e)

__device__ __forceinline__ bf16x8 cvt8(const float* p) {
    float4 u0 = *(const float4*)p;
    float4 u1 = *(const float4*)(p + 4);
    bf16x8 v = { (bf16)u0.x, (bf16)u0.y, (bf16)u0.z, (bf16)u0.w,
                 (bf16)u1.x, (bf16)u1.y, (bf16)u1.z, (bf16)u1.w };
    return v;
}

// async global->LDS, 16 B per lane (LDS dest = wave-uniform base + lane*16).
__device__ __forceinline__ void async16(const bf16* g, bf16* l) {
    __builtin_amdgcn_global_load_lds(
        (const __attribute__((address_space(1))) void*)g,
        (__attribute__((address_space(3))) void*)l, 16, 0, 0);
}

// ---------------------------------------------------------------------------
// Kernel 0: merged f32 -> bf16 cast for all three tensors (R16: one launch
// instead of three — per-kernel work sums to ~115 µs vs dur_us ~176, so
// ~60 µs is inter-dispatch overhead; 6 -> 4 launches). Segments:
//   [0,         524288) -> x      (2*2048*1024 / 8)
//   [524288,    917504) -> qkv_w  (3*1024*1024 / 8)
//   [917504,   1048576) -> out_w  (1024*1024   / 8)
// Total 1048576 chunks = 4096 blocks x 256 threads exactly.
// ---------------------------------------------------------------------------
static constexpr int X8 = 524288;
static constexpr int W8 = 917504;   // X8 + 393216
static constexpr int T8 = 1048576;  // W8 + 131072

__global__ __launch_bounds__(256)
void k_cast_all(const float* __restrict__ x, const float* __restrict__ qkv_w,
                const float* __restrict__ out_w,
                bf16* __restrict__ xb, bf16* __restrict__ wqb,
                bf16* __restrict__ wob)
{
    int i = blockIdx.x * 256 + threadIdx.x;
    if (i < X8) {
        *(bf16x8*)&xb[(size_t)i * 8] = cvt8(&x[(size_t)i * 8]);
    } else if (i < W8) {
        int j = i - X8;
        *(bf16x8*)&wqb[(size_t)j * 8] = cvt8(&qkv_w[(size_t)j * 8]);
    } else if (i < T8) {
        int j = i - W8;
        *(bf16x8*)&wob[(size_t)j * 8] = cvt8(&out_w[(size_t)j * 8]);
    }
}

// ---------------------------------------------------------------------------
// Kernel 1: QKV projection, 128x128 tile, BK=32 — R1 version (syncthreads,
// single-buffer). R5 measured the counted-vmcnt pipeline variant at 45.4 µs
// vs <=42 for this one: at 12 waves/CU, wave-level TLP already hides the
// staging drain (m131-m140 precedent); the extra barrier per K-step net-lost.
// Q -> [B,H,T,64] (pre-scaled), K -> [B,H,T,64], V -> transposed [B,H,64,T].
// ---------------------------------------------------------------------------
__global__ __launch_bounds__(256)
void k_qkv(const bf16* __restrict__ x, const bf16* __restrict__ w,
           const float* __restrict__ bias,
           bf16* __restrict__ Qb, bf16* __restrict__ Kb, bf16* __restrict__ VbT)
{
    __shared__ bf16 As[128 * 32];   // 8 KB, flat
    __shared__ bf16 Ws[128 * 32];

    const int tid  = threadIdx.x;
    const int wv   = tid >> 6;
    const int lane = tid & 63;
    const int lr   = lane & 15;
    const int lk   = lane >> 4;
    const int wm   = wv >> 1, wn = wv & 1;
    const int m0   = blockIdx.x * 128;
    const int n0   = blockIdx.y * 128;

    const int sRow = tid >> 2;           // 0..63
    const int sCol = (tid & 3) * 8;      // 0,8,16,24
    const int sOff = sRow * 32 + sCol;   // = 16*tid bytes

    f32x4 acc[4][4] = {};

    for (int kt = 0; kt < 1024; kt += 32) {
        __syncthreads();
        async16(&x[(size_t)(m0 + sRow     ) * 1024 + kt + sCol], &As[sOff]);
        async16(&x[(size_t)(m0 + 64 + sRow) * 1024 + kt + sCol], &As[64 * 32 + sOff]);
        async16(&w[(size_t)(n0 + sRow     ) * 1024 + kt + sCol], &Ws[sOff]);
        async16(&w[(size_t)(n0 + 64 + sRow) * 1024 + kt + sCol], &Ws[64 * 32 + sOff]);
        __syncthreads();

        bf16x8 a[4], b[4];
        #pragma unroll
        for (int i = 0; i < 4; i++) {
            a[i] = *(const bf16x8*)&As[(wm * 64 + i * 16 + lr) * 32 + lk * 8];
            b[i] = *(const bf16x8*)&Ws[(wn * 64 + i * 16 + lr) * 32 + lk * 8];
        }
        #pragma unroll
        for (int i = 0; i < 4; i++)
            #pragma unroll
            for (int j = 0; j < 4; j++)
                acc[i][j] = MFMA16(a[i], b[j], acc[i][j]);
    }

    // C/D layout: col = lane&15, row = (lane>>4)*4 + reg
    #pragma unroll
    for (int i = 0; i < 4; i++) {
        #pragma unroll
        for (int j = 0; j < 4; j++) {
            const int gm0 = m0 + wm * 64 + i * 16 + lk * 4;
            const int gn  = n0 + wn * 64 + j * 16 + lr;
            const int sel = gn >> 10;
            const int rem = gn & 1023;
            const int h   = rem >> 6;
            const int hd  = rem & 63;
            const int bb  = gm0 >> 11;
            const int t0  = gm0 & 2047;
            if (sel == 2) {
                bf16x4 p;
                #pragma unroll
                for (int r = 0; r < 4; r++) p[r] = (bf16)(acc[i][j][r] + bias[gn]);
                *(bf16x4*)&VbT[((size_t)(bb * NH + h) * HD + hd) * SEQ + t0] = p;
            } else {
                #pragma unroll
                for (int r = 0; r < 4; r++) {
                    float v = acc[i][j][r] + bias[gn];
                    size_t idx = ((size_t)(bb * NH + h) * SEQ + t0 + r) * HD + hd;
                    if (sel == 0) Qb[idx] = (bf16)(v * QSCALE);
                    else          Kb[idx] = (bf16)v;
                }
            }
        }
    }
}

// ---------------------------------------------------------------------------
// Kernel 2: causal flash attention — exact R1 version (best measured).
// QBLK=64, 4 waves x 16 q; double-buffered K/V staging via global_load_lds
// issued one tile ahead; counted s_waitcnt vmcnt(4) + raw s_barrier (loads
// survive barriers); 16B-chunk XOR swizzle with pre-swizzled GLOBAL source
// (linear LDS dest, both-sides-or-neither); no-max softmax with HW exp,
// transposed scores S^T = K·Q^T. LDS 40 KB -> 4 blocks/CU; grid 1024
// all-resident; serpentine qt-mapping balances per-CU work.
// R2 lesson: QBLK=128 via fatter waves (VGPR 80, 2 blk/CU) = 64 µs. FAIL.
// R15 lesson: QBLK=128 via 8 waves x 16 q (512 thr, VGPR 40) = 53 µs. FAIL.
// Both confirm: cost = per-tile serial chain x tiles/CU; wider blocks add
// barrier-arrival coupling. QBLK=64 / 4-wave is the measured optimum.
// ---------------------------------------------------------------------------
__global__ __launch_bounds__(256)
void k_attn(const bf16* __restrict__ Qb, const bf16* __restrict__ Kb,
            const bf16* __restrict__ VbT, bf16* __restrict__ AO)
{
    __shared__ bf16 Ks[2][64 * 64];   // [buf][key][hd], swizzled, 8 KB each
    __shared__ bf16 Vt[2][64 * 64];   // [buf][hd][key], swizzled
    __shared__ bf16 Ps[64 * 64];      // [q][key], swizzled, wave-local rows

    const int tid  = threadIdx.x;
    const int wv   = tid >> 6;
    const int lane = tid & 63;
    const int lr   = lane & 15;
    const int lk   = lane >> 4;
    const int bh   = blockIdx.y;
    const int qt   = ((bh >> 3) & 1) ? (31 - (int)blockIdx.x) : (int)blockIdx.x;

    const bf16* Qp  = Qb  + (size_t)bh * SEQ * HD;
    const bf16* Kp  = Kb  + (size_t)bh * SEQ * HD;
    const bf16* Vtp = VbT + (size_t)bh * HD * SEQ;

    const int qg = qt * 64 + wv * 16 + lr;    // this lane's query row

    // Q as B-operand: b[n=lr][k=lk*8+e] (loop-invariant)
    bf16x8 qf[2];
    qf[0] = *(const bf16x8*)&Qp[(size_t)qg * HD +      lk * 8];
    qf[1] = *(const bf16x8*)&Qp[(size_t)qg * HD + 32 + lk * 8];

    f32x4 ot[4] = {};          // O^T: col=q(=lr), row=hd=jh*16+lk*4+r
    float lsum = 0.f;

    // Staging geometry: per round i in {0,1}, thread covers row i*32+(tid>>3),
    // LDS dest linear (elem = i*2048 + tid*8); global source chunk
    // pre-swizzled: chunk = (tid&7) ^ (row&7).
    const int srow   = tid >> 3;                       // 0..31
    const int sgcol  = ((tid & 7) ^ (srow & 7)) * 8;   // swizzled global col
    const int sldse  = tid * 8;                        // lds elem in round
    const int swz    = lr & 7;                         // read-side swizzle key

    auto stage = [&](int buf, int k0) {
        async16(&Kp [(size_t)(k0 + srow     ) * HD  + sgcol], &Ks[buf][       sldse]);
        async16(&Kp [(size_t)(k0 + 32 + srow) * HD  + sgcol], &Ks[buf][2048 + sldse]);
        async16(&Vtp[(size_t)(srow          ) * SEQ + k0 + sgcol], &Vt[buf][       sldse]);
        async16(&Vtp[(size_t)(32 + srow     ) * SEQ + k0 + sgcol], &Vt[buf][2048 + sldse]);
    };

    stage(0, 0);   // prologue: tile 0 in flight

    for (int kt = 0; kt <= qt; kt++) {
        const int p = kt & 1;
        if (kt < qt) {
            stage(p ^ 1, (kt + 1) * 64);                    // prefetch next tile
            asm volatile("s_waitcnt vmcnt(4)" ::: "memory"); // cur landed, next 4 in flight
        } else {
            asm volatile("s_waitcnt vmcnt(0)" ::: "memory"); // last tile: drain
        }
        __builtin_amdgcn_s_barrier();

        // S^T[key][q]: A = K rows (LDS), B = Q frags; row=key=j*16+lk*4+r, col=q=lr
        f32x4 s[4] = {};
        #pragma unroll
        for (int j = 0; j < 4; j++) {
            #pragma unroll
            for (int c = 0; c < 2; c++) {
                bf16x8 ka = *(const bf16x8*)
                    &Ks[p][(j * 16 + lr) * 64 + (((4 * c + lk) ^ swz) << 3)];
                s[j] = MFMA16(ka, qf[c], s[j]);
            }
        }

        // no-max softmax with HW exp; masked -> 0 on the diagonal tile
        const int k0 = kt * 64;
        const bool diag = (kt == qt);
        #pragma unroll
        for (int j = 0; j < 4; j++) {
            const int keyb = k0 + j * 16 + lk * 4;
            f32x4 pv;
            #pragma unroll
            for (int r = 0; r < 4; r++) {
                float e = __builtin_amdgcn_exp2f(s[j][r]);
                if (diag) e = (keyb + r > qg) ? 0.f : e;
                pv[r] = e;
            }
            s[j] = pv;
            lsum += (pv[0] + pv[1]) + (pv[2] + pv[3]);
        }

        // P -> LDS [q][key] (swizzled 16B chunks; wave-local rows, no barrier)
        #pragma unroll
        for (int j = 0; j < 4; j++) {
            bf16x4 p4 = { (bf16)s[j][0], (bf16)s[j][1], (bf16)s[j][2], (bf16)s[j][3] };
            *(bf16x4*)&Ps[(wv * 16 + lr) * 64 +
                          (((2 * j + (lk >> 1)) ^ swz) << 3) + ((lk & 1) << 2)] = p4;
        }

        // O^T += Vt · P^T : MFMA(a = Vt rows [hd][key], b = Ps rows [q][key])
        #pragma unroll
        for (int c = 0; c < 2; c++) {
            bf16x8 pb = *(const bf16x8*)
                &Ps[(wv * 16 + lr) * 64 + (((4 * c + lk) ^ swz) << 3)];
            #pragma unroll
            for (int jh = 0; jh < 4; jh++) {
                bf16x8 va = *(const bf16x8*)
                    &Vt[p][(jh * 16 + lr) * 64 + (((4 * c + lk) ^ swz) << 3)];
                ot[jh] = MFMA16(va, pb, ot[jh]);
            }
        }

        asm volatile("" ::: "memory");
        __builtin_amdgcn_s_barrier();   // protect buf[p^1] before next stage
    }

    // final l reduction: 2 shfls once per kernel (lanes lr, lr+16, lr+32, lr+48)
    lsum += __shfl_xor(lsum, 16);
    lsum += __shfl_xor(lsum, 32);

    // epilogue: AO[b, q, h_*64 + hd] = O/l ; lane writes 4 consecutive hd (b64)
    const float inv = 1.0f / lsum;
    const int b_ = bh >> 4, h_ = bh & 15;
    const size_t base = ((size_t)(b_ * SEQ + qg)) * D_MODEL + h_ * HD;
    #pragma unroll
    for (int jh = 0; jh < 4; jh++) {
        bf16x4 o4 = { (bf16)(ot[jh][0] * inv), (bf16)(ot[jh][1] * inv),
                      (bf16)(ot[jh][2] * inv), (bf16)(ot[jh][3] * inv) };
        *(bf16x4*)&AO[base + jh * 16 + lk * 4] = o4;
    }
}

// ---------------------------------------------------------------------------
// Kernel 3: output projection, 128x64 tile, BK=32 — R1 version (syncthreads,
// single-buffer; pipeline variant regressed, see k_qkv note).
// ---------------------------------------------------------------------------
__global__ __launch_bounds__(256)
void k_oproj(const bf16* __restrict__ a_, const bf16* __restrict__ w,
             const float* __restrict__ bias, float* __restrict__ out)
{
    __shared__ bf16 As[128 * 32];
    __shared__ bf16 Ws[64 * 32];

    const int tid  = threadIdx.x;
    const int wv   = tid >> 6;
    const int lane = tid & 63;
    const int lr   = lane & 15;
    const int lk   = lane >> 4;
    const int wm   = wv >> 1, wn = wv & 1;
    const int m0   = blockIdx.x * 128;
    const int n0   = blockIdx.y * 64;

    const int sRow = tid >> 2;
    const int sCol = (tid & 3) * 8;
    const int sOff = sRow * 32 + sCol;

    f32x4 acc[4][2] = {};

    for (int kt = 0; kt < 1024; kt += 32) {
        __syncthreads();
        async16(&a_[(size_t)(m0 + sRow     ) * 1024 + kt + sCol], &As[sOff]);
        async16(&a_[(size_t)(m0 + 64 + sRow) * 1024 + kt + sCol], &As[64 * 32 + sOff]);
        async16(&w [(size_t)(n0 + sRow     ) * 1024 + kt + sCol], &Ws[sOff]);
        __syncthreads();

        bf16x8 a[4], b[2];
        #pragma unroll
        for (int i = 0; i < 4; i++)
            a[i] = *(const bf16x8*)&As[(wm * 64 + i * 16 + lr) * 32 + lk * 8];
        #pragma unroll
        for (int j = 0; j < 2; j++)
            b[j] = *(const bf16x8*)&Ws[(wn * 32 + j * 16 + lr) * 32 + lk * 8];
        #pragma unroll
        for (int i = 0; i < 4; i++)
            #pragma unroll
            for (int j = 0; j < 2; j++)
                acc[i][j] = MFMA16(a[i], b[j], acc[i][j]);
    }

    #pragma unroll
    for (int i = 0; i < 4; i++) {
        #pragma unroll
        for (int j = 0; j < 2; j++) {
            #pragma unroll
            for (int r = 0; r < 4; r++) {
                int gm = m0 + wm * 64 + i * 16 + lk * 4 + r;
                int gn = n0 + wn * 32 + j * 16 + lr;
                out[(size_t)gm * 1024 + gn] = acc[i][j][r] + bias[gn];
            }
        }
    }
}

// ---------------------------------------------------------------------------
extern "C" void kernel_launch(void* const* d_in, const int* in_sizes, int n_in,
                              void* d_out, int out_size, void* d_ws, size_t ws_size,
                              hipStream_t stream)
{
    const float* x     = (const float*)d_in[0];
    const float* qkv_w = (const float*)d_in[1];
    const float* qkv_b = (const float*)d_in[2];
    const float* out_w = (const float*)d_in[3];
    const float* out_b = (const float*)d_in[4];
    float* out = (float*)d_out;

    const size_t SZ = (size_t)NB * NH * SEQ * HD;      // 4,194,304
    bf16* Qb  = (bf16*)d_ws;
    bf16* Kb  = Qb + SZ;
    bf16* VbT = Kb + SZ;
    bf16* AO  = VbT + SZ;
    bf16* xb  = AO + SZ;
    bf16* wqb = xb + SZ;
    bf16* wob = wqb + (size_t)3 * D_MODEL * D_MODEL;

    hipLaunchKernelGGL(k_cast_all, dim3(4096), dim3(256), 0, stream,
                       x, qkv_w, out_w, xb, wqb, wob);

    hipLaunchKernelGGL(k_qkv, dim3(32, 24), dim3(256), 0, stream,
                       xb, wqb, qkv_b, Qb, Kb, VbT);
    hipLaunchKernelGGL(k_attn, dim3(32, 32), dim3(256), 0, stream,
                       Qb, Kb, VbT, AO);
    hipLaunchKernelGGL(k_oproj, dim3(32, 16), dim3(256), 0, stream,
                       AO, wob, out_b, out);
}